// Round 1
// 516.682 us; speedup vs baseline: 1.0001x; 1.0001x over previous
//
#include <hip/hip_runtime.h>

// SoftPool2d: x (16, 96, 256, 256) f32, 2x2 window, stride 2, no pad.
// out (16, 96, 128, 128) f32. out[p] = sum(t_i * softmax(t)_i) over 4 taps.
//
// Streaming, memory-bound. Key change vs previous version: every global load
// is UNIT-STRIDE across lanes (lane i reads the f32x4 at col 4i), so each
// global_load_dwordx4 covers a full contiguous 1 KB input row per wave with
// 100% cache-line utilization. The old mapping gave each lane 8 contiguous
// cols (32 B) -> two interleaved 32B-strided loads, each touching every line
// half-used (hostile to nt no-allocate loads).
//
// Each thread: 4 input rows x 4 cols (4x 16 B unit-stride loads, MLP=4)
//              -> 2x2 output pixels (2x 8 B coalesced nt stores).
//
// NOTE: __builtin_nontemporal_* requires a native vector type, not HIP's
// float4 struct -> use ext_vector_type.

#define H_IN   256
#define W_IN   256
#define H_OUT  128
#define W_OUT  128

typedef float f32x4 __attribute__((ext_vector_type(4)));
typedef float f32x2 __attribute__((ext_vector_type(2)));

__device__ __forceinline__ float softpool4(float a, float b, float c, float d) {
    float m  = fmaxf(fmaxf(a, b), fmaxf(c, d));
    float ea = __expf(a - m);
    float eb = __expf(b - m);
    float ec = __expf(c - m);
    float ed = __expf(d - m);
    float num = a * ea + b * eb + c * ec + d * ed;
    float den = (ea + eb) + (ec + ed);
    return num * __builtin_amdgcn_rcpf(den);
}

__global__ __launch_bounds__(256)
void SoftPool2d_850403524762_kernel(const float* __restrict__ x,
                                    float* __restrict__ out,
                                    int n_threads) {
    int tid = blockIdx.x * blockDim.x + threadIdx.x;
    if (tid >= n_threads) return;

    // Wave-level layout: all 64 lanes of a wave share r2; c4 = lane id.
    // Lane i loads 16 B at byte offset 16*i of each input row -> one dense
    // 1 KB row read per wave per load instruction.
    int c4 = tid & 63;             // column quad: input cols 4*c4 .. 4*c4+3
    int r2 = tid >> 6;             // output row-pair id
    int hp = r2 & (H_OUT / 2 - 1); // row pair within image (H_OUT/2 = 64)
    int bc = r2 >> 6;              // flattened (b*c)

    const float* p = x + (size_t)bc * (H_IN * W_IN)
                       + (size_t)(4 * hp) * W_IN
                       + 4 * c4;

    // 4 input rows, one unit-stride 16 B load each (4 loads in flight)
    const f32x4 t0 = __builtin_nontemporal_load((const f32x4*)(p));
    const f32x4 b0 = __builtin_nontemporal_load((const f32x4*)(p + W_IN));
    const f32x4 t1 = __builtin_nontemporal_load((const f32x4*)(p + 2 * W_IN));
    const f32x4 b1 = __builtin_nontemporal_load((const f32x4*)(p + 3 * W_IN));

    // Each f32x4 holds two complete horizontal window-pairs (cols are even-
    // aligned), so both 2x2 windows per row-pair are lane-local.
    f32x2 o0, o1;
    o0.x = softpool4(t0.x, t0.y, b0.x, b0.y);
    o0.y = softpool4(t0.z, t0.w, b0.z, b0.w);
    o1.x = softpool4(t1.x, t1.y, b1.x, b1.y);
    o1.y = softpool4(t1.z, t1.w, b1.z, b1.w);

    float* op = out + (size_t)bc * (H_OUT * W_OUT)
                    + (size_t)(2 * hp) * W_OUT
                    + 2 * c4;
    __builtin_nontemporal_store(o0, (f32x2*)op);           // output row 2*hp
    __builtin_nontemporal_store(o1, (f32x2*)(op + W_OUT)); // output row 2*hp+1
}

extern "C" void kernel_launch(void* const* d_in, const int* in_sizes, int n_in,
                              void* d_out, int out_size, void* d_ws, size_t ws_size,
                              hipStream_t stream) {
    const float* x  = (const float*)d_in[0];
    float* out      = (float*)d_out;

    // One thread per 2x2 output patch: 16 * 96 * (128/2) * (128/2) threads
    const int n_threads = 16 * 96 * (H_OUT / 2) * (W_OUT / 2); // 6,291,456
    const int block     = 256;
    const int grid      = (n_threads + block - 1) / block;     // 24,576

    SoftPool2d_850403524762_kernel<<<grid, block, 0, stream>>>(x, out, n_threads);
}